// Round 8
// baseline (396.441 us; speedup 1.0000x reference)
//
#include <hip/hip_runtime.h>
#include <hip/hip_bf16.h>

// Problem constants
#define B_SZ 8192
#define D_SZ 512
#define K_SZ 4096
#define L_SZ 16
#define M_ALL (B_SZ + K_SZ)   // 12288 rows: targets stacked over codebook

typedef __attribute__((ext_vector_type(8))) short short8v;      // 8 bf16
typedef __attribute__((ext_vector_type(4))) float f32x4;
typedef _Float16 half8v __attribute__((ext_vector_type(8)));    // 8 fp16 = 16B
typedef _Float16 h2 __attribute__((ext_vector_type(2)));        // packed fp16 pair
struct H2x4 { h2 a, b, c, d; };                                 // = one half8v

typedef const __attribute__((address_space(1))) void gvoid;
typedef __attribute__((address_space(3))) void lvoid;

static __device__ __forceinline__ h2 habs2(h2 a) {
    unsigned u = __builtin_bit_cast(unsigned, a) & 0x7FFF7FFFu;
    return __builtin_bit_cast(h2, u);
}
static __device__ __forceinline__ h2 hmax2(h2 a, h2 b) {
#if __has_builtin(__builtin_elementwise_max)
    return __builtin_elementwise_max(a, b);
#else
    h2 r; r[0] = a[0] > b[0] ? a[0] : b[0]; r[1] = a[1] > b[1] ? a[1] : b[1]; return r;
#endif
}

// ---------------------------------------------------------------------------
// Kernel 1: cast targets+codebook (fp32) into one stacked bf16 matrix [12288 x 512]
// ---------------------------------------------------------------------------
__global__ void cast_bf16_kernel(const float* __restrict__ targets,
                                 const float* __restrict__ codebook,
                                 __hip_bfloat16* __restrict__ abf) {
    int idx = blockIdx.x * blockDim.x + threadIdx.x;
    const int total4 = (M_ALL * D_SZ) / 4;
    if (idx >= total4) return;
    int base = idx * 4;
    const float* src = (base < B_SZ * D_SZ) ? (targets + base)
                                            : (codebook + (base - B_SZ * D_SZ));
    float4 v = *(const float4*)src;
    abf[base + 0] = __float2bfloat16(v.x);
    abf[base + 1] = __float2bfloat16(v.y);
    abf[base + 2] = __float2bfloat16(v.z);
    abf[base + 3] = __float2bfloat16(v.w);
}

// ---------------------------------------------------------------------------
// Kernel 1b: exact fp64 codebook row norms^2 (for algebraic ||r||^2 update)
// ---------------------------------------------------------------------------
__global__ void cn2_kernel(const float* __restrict__ codebook,
                           double* __restrict__ cn2) {
    int row  = blockIdx.x * 4 + (threadIdx.x >> 6);
    int lane = threadIdx.x & 63;
    const float* r = codebook + (size_t)row * D_SZ;
    double s = 0.0;
#pragma unroll
    for (int j = 0; j < 8; j++) { double v = (double)r[lane + 64 * j]; s += v * v; }
#pragma unroll
    for (int o = 32; o > 0; o >>= 1) s += __shfl_down(s, o, 64);
    if (lane == 0) cn2[row] = s;
}

// ---------------------------------------------------------------------------
// Kernel 2: S = A * B^T -> fp16 [M x 4096]. 256x128 tile, 8 waves, BK=32,
// 16x16x32 MFMA. EXACT R6 version (best measured total 334.2 us). Scheduling
// variants (BK=64, packed epilogue, 2-phase dbuf) all neutral-to-negative:
// GEMM sits at its structure family's shape curve for 51.5 GFLOP.
// ---------------------------------------------------------------------------
#define BM 256
#define BN 128
#define BK 32   // bf16 elems: 64 B per LDS row, unpadded

__global__ __launch_bounds__(512)
void gemm_bt_kernel(const __hip_bfloat16* __restrict__ A,
                    const __hip_bfloat16* __restrict__ Bm,
                    _Float16* __restrict__ C) {
    __shared__ short As[BM * BK];   // 16 KB
    __shared__ short Bs[BN * BK];   // 8 KB
    const int tid  = threadIdx.x;
    const int bm   = blockIdx.y * BM;
    const int bn   = blockIdx.x * BN;
    const int wave = tid >> 6, lane = tid & 63;
    const int wm = (wave >> 1) * 64;     // 0,64,128,192
    const int wn = (wave & 1) * 64;      // 0,64
    const int row16 = lane & 15, quad = lane >> 4;
    const int koff = quad * 8;

    f32x4 acc[4][4] = {};

    const short* Ag = (const short*)A;
    const short* Bg = (const short*)Bm;
    const int srow = lane >> 2;          // 0..15 within a 16-row group
    const int scol = (lane & 3) * 8;     // elem offset 0/8/16/24 (16 B chunks)

    for (int k0 = 0; k0 < D_SZ; k0 += BK) {
        __syncthreads();   // protect previous iteration's fragment reads
        // A: 256 rows = 8 waves x 2 groups of 16
#pragma unroll
        for (int c = 0; c < 2; c++) {
            int row = wave * 32 + c * 16 + srow;
            __builtin_amdgcn_global_load_lds(
                (gvoid*)(Ag + (size_t)(bm + row) * D_SZ + k0 + scol),
                (lvoid*)(As + row * BK + scol), 16, 0, 0);
        }
        // B: 128 rows = 8 waves x 1 group of 16
        {
            int row = wave * 16 + srow;
            __builtin_amdgcn_global_load_lds(
                (gvoid*)(Bg + (size_t)(bn + row) * D_SZ + k0 + scol),
                (lvoid*)(Bs + row * BK + scol), 16, 0, 0);
        }
        __syncthreads();   // drains vmcnt -> LDS tiles complete

        short8v af[4], bf[4];
#pragma unroll
        for (int i = 0; i < 4; i++)
            af[i] = *(const short8v*)(As + (wm + i * 16 + row16) * BK + koff);
#pragma unroll
        for (int j = 0; j < 4; j++)
            bf[j] = *(const short8v*)(Bs + (wn + j * 16 + row16) * BK + koff);
#pragma unroll
        for (int i = 0; i < 4; i++)
#pragma unroll
            for (int j = 0; j < 4; j++)
                acc[i][j] = __builtin_amdgcn_mfma_f32_16x16x32_bf16(af[i], bf[j], acc[i][j], 0, 0, 0);
    }

    // C/D layout: col = lane&15, row = quad*4 + reg  [m89/m91 verified]
    if (bm < B_SZ) {
        // score region: written once, read once by pursuit -> non-temporal
#pragma unroll
        for (int i = 0; i < 4; i++) {
            int grow = bm + wm + i * 16 + quad * 4;
#pragma unroll
            for (int j = 0; j < 4; j++) {
                int gcol = bn + wn + j * 16 + row16;
#pragma unroll
                for (int r = 0; r < 4; r++)
                    __builtin_nontemporal_store((_Float16)acc[i][j][r],
                                                &C[(size_t)(grow + r) * K_SZ + gcol]);
            }
        }
    } else {
        // Gram region: hot random-access data for pursuit -> keep cached
#pragma unroll
        for (int i = 0; i < 4; i++) {
            int grow = bm + wm + i * 16 + quad * 4;
#pragma unroll
            for (int j = 0; j < 4; j++) {
                int gcol = bn + wn + j * 16 + row16;
#pragma unroll
                for (int r = 0; r < 4; r++)
                    C[(size_t)(grow + r) * K_SZ + gcol] = (_Float16)acc[i][j][r];
            }
        }
    }
}

// ---------------------------------------------------------------------------
// Kernel 3: pursuit, wave-per-row, g in LDS (round-0 structure) + NEW
// SPECULATIVE ARGMAX PREFETCH. Evidence: effective fetch BW tracks per-wave
// MLP (R3 8w/CU=1.77 TB/s, R0 12w=2.86); the ~700cy codebook+Gram load sits
// after the scan on every step's serial chain, and nc==1 ~always (score top
// gap ~150 >> MARGIN=1.5). So: track lane argmax during the fused update,
// wave-reduce (value,index), and issue codebook+Gram+cn2 loads for argK
// BEFORE the scan -- latency hides under scan+threshold. Guard: argK's
// |g|=M>=thr so argK is always a candidate; (nc==1 && cand[0]==argK) -> use
// speculative data; else -> existing general rescore path (covers diagonal-
// patch staleness and fp16 ties). Threshold/scan/tie-break semantics
// unchanged from the verified round-0 kernel.
// ---------------------------------------------------------------------------
#define MAXC 16
#define MARGIN 1.5f

__global__ __launch_bounds__(256, 4)
void pursuit_kernel(const float* __restrict__ targets,
                    const float* __restrict__ codebook,
                    const _Float16* __restrict__ S,   // [12288 x 4096]; rows >=8192 are Gram
                    const double* __restrict__ cn2,   // [4096] exact ||c_k||^2
                    float* __restrict__ out) {
    const int wave = threadIdx.x >> 6;
    const int lane = threadIdx.x & 63;
    const int b = blockIdx.x * 4 + wave;
    const int lane8 = lane * 8;

    __shared__ alignas(16) _Float16 g_s[4][K_SZ];
    __shared__ int s_cnt[4];
    __shared__ int s_cand[4][MAXC];
    _Float16* g = g_s[wave];
    int* cnt  = &s_cnt[wave];
    int* cand = s_cand[wave];

    // ---- init: score row -> LDS (non-temporal); track lane max + group ----
    float bestv = -1.0f; int bestc = 0;
    {
        const _Float16* g0 = S + (size_t)b * K_SZ + lane8;
#pragma unroll
        for (int c = 0; c < 8; c++) {
            half8v h = __builtin_nontemporal_load((const half8v*)(g0 + c * 512));
            *(half8v*)&g[c * 512 + lane8] = h;
            H2x4 u = __builtin_bit_cast(H2x4, h);
            h2 g2 = hmax2(hmax2(habs2(u.a), habs2(u.b)),
                          hmax2(habs2(u.c), habs2(u.d)));
            float gm = fmaxf((float)g2[0], (float)g2[1]);
            if (gm > bestv) { bestv = gm; bestc = c; }
        }
    }

    // ---- lane-private fp64 residual + tn2 (non-temporal target read) ----
    double rres[8];
    double loc = 0.0;
    {
        const float* tg = targets + (size_t)b * D_SZ + lane8;
        f32x4 t0 = __builtin_nontemporal_load((const f32x4*)tg);
        f32x4 t1 = __builtin_nontemporal_load((const f32x4*)(tg + 4));
        rres[0] = t0[0]; rres[1] = t0[1]; rres[2] = t0[2]; rres[3] = t0[3];
        rres[4] = t1[0]; rres[5] = t1[1]; rres[6] = t1[2]; rres[7] = t1[3];
#pragma unroll
        for (int e = 0; e < 8; e++) loc += rres[e] * rres[e];
    }
#pragma unroll
    for (int o = 32; o > 0; o >>= 1) loc += __shfl_xor(loc, o, 64);
    double rn2 = loc;
    const bool tgt_ok = (sqrt(loc) >= 1e-8);

    float* out_seq  = out + (size_t)b * L_SZ;
    float* out_mask = out + (size_t)B_SZ * L_SZ + (size_t)b * L_SZ;
    float* out_res  = out + (size_t)2 * B_SZ * L_SZ + (size_t)b * D_SZ;

    double decay = 1.0;

    for (int t = 0; t < L_SZ; t++) {
        decay *= 0.95;
        bool active = (sqrt(rn2) >= 0.01) && tgt_ok;   // wave-uniform
        if (!active) {                                 // stays inactive forever
            if (lane == 0)
                for (int tt = t; tt < L_SZ; tt++) {
                    __builtin_nontemporal_store(0.0f, &out_seq[tt]);
                    __builtin_nontemporal_store(0.0f, &out_mask[tt]);
                }
            break;
        }

        // ---- resolve lane-argmax element (re-read winning group) ----
        int lk;
        {
            half8v h = *(const half8v*)&g[bestc * 512 + lane8];
            int beste = 0;
#pragma unroll
            for (int e = 7; e >= 0; e--)              // descending -> lowest match wins
                if (fabsf((float)h[e]) >= bestv) beste = e;
            lk = bestc * 512 + lane8 + beste;
        }

        // ---- wave argmax reduce: value desc, index asc (packed 64-bit key) ----
        unsigned long long key =
            ((unsigned long long)__builtin_bit_cast(unsigned, bestv) << 32)
            | (unsigned long long)(0xFFFFFFFFu - (unsigned)lk);
#pragma unroll
        for (int o = 32; o > 0; o >>= 1) {
            unsigned long long other = __shfl_xor(key, o, 64);
            key = other > key ? other : key;
        }
        const float Mv = __builtin_bit_cast(float, (unsigned)(key >> 32));
        int argK = (int)(0xFFFFFFFFu - (unsigned)(key & 0xFFFFFFFFull));
        argK = __builtin_amdgcn_readfirstlane(argK);
        const float thr = Mv - MARGIN;

        // ---- SPECULATIVE loads for argK: issued BEFORE the scan so the
        //      L2/HBM latency hides under scan+collection. nc==1 ~always,
        //      and then cand[0]==argK necessarily. ----
        float4 c0, c1;
        half8v Gh[8];
        {
            const float* cr = codebook + (size_t)argK * D_SZ + lane8;
            const _Float16* Gp = S + (size_t)(B_SZ + argK) * K_SZ + lane8;
            c0 = *(const float4*)cr;
            c1 = *(const float4*)(cr + 4);
#pragma unroll
            for (int c = 0; c < 8; c++) Gh[c] = *(const half8v*)(Gp + c * 512);
        }
        const double cn2spec = cn2[argK];

        // ---- candidate collection: unchanged semantics ----
        if (lane == 0) *cnt = 0;
        if (bestv >= thr) {
#pragma unroll
            for (int c = 0; c < 8; c++) {
                half8v h = *(const half8v*)&g[c * 512 + lane8];
#pragma unroll
                for (int e = 0; e < 8; e++) {
                    float f = fabsf((float)h[e]);
                    if (f >= thr) {
                        int q = atomicAdd(cnt, 1);
                        if (q < MAXC) cand[q] = c * 512 + lane8 + e;
                    }
                }
            }
        }
        __threadfence_block();
        int nc = min(*cnt, MAXC);
        int ck = __builtin_amdgcn_readfirstlane(cand[0]);   // nc >= 1 (argK qualifies)

        int bk; double bv; double cn2bk;
        if (nc == 1 && ck == argK) {
            // fast path: speculation confirmed; data already in flight/regs
            bk = argK; cn2bk = cn2spec;
            double s = rres[0] * (double)c0.x + rres[1] * (double)c0.y
                     + rres[2] * (double)c0.z + rres[3] * (double)c0.w
                     + rres[4] * (double)c1.x + rres[5] * (double)c1.y
                     + rres[6] * (double)c1.z + rres[7] * (double)c1.w;
#pragma unroll
            for (int o = 32; o > 0; o >>= 1) s += __shfl_xor(s, o, 64);
            bv = s;
        } else {
            // general path: exact fp64 rescore of all candidates + winner reload
            bk = -1; bv = 0.0;
            for (int ci = 0; ci < nc; ci++) {
                int k = __builtin_amdgcn_readfirstlane(cand[ci]);
                const float* cr = codebook + (size_t)k * D_SZ + lane8;
                float4 d0 = *(const float4*)cr;
                float4 d1 = *(const float4*)(cr + 4);
                double s = rres[0] * (double)d0.x + rres[1] * (double)d0.y
                         + rres[2] * (double)d0.z + rres[3] * (double)d0.w
                         + rres[4] * (double)d1.x + rres[5] * (double)d1.y
                         + rres[6] * (double)d1.z + rres[7] * (double)d1.w;
#pragma unroll
                for (int o = 32; o > 0; o >>= 1) s += __shfl_xor(s, o, 64);
                if (bk < 0 || fabs(s) > fabs(bv) ||
                    (fabs(s) == fabs(bv) && k < bk)) { bk = k; bv = s; }
            }
            const float* cr = codebook + (size_t)bk * D_SZ + lane8;   // winner row
            const _Float16* Gp = S + (size_t)(B_SZ + bk) * K_SZ + lane8;
            c0 = *(const float4*)cr;
            c1 = *(const float4*)(cr + 4);
#pragma unroll
            for (int c = 0; c < 8; c++) Gh[c] = *(const half8v*)(Gp + c * 512);
            cn2bk = cn2[bk];
        }

        // ---- decision + exact ||r||^2 identity + outputs ----
        double sd = ((bv >= 0.0) ? 1.0 : -1.0) * decay;
        rn2 = rn2 - 2.0 * sd * bv + sd * sd * cn2bk;
        if (lane == 0) {
            __builtin_nontemporal_store((float)((bv >= 0.0) ? bk : (-bk - 1)), &out_seq[t]);
            __builtin_nontemporal_store(1.0f, &out_mask[t]);
        }
        const float sdf = (float)sd;
        h2 sdh2; sdh2[0] = (_Float16)sdf; sdh2[1] = (_Float16)sdf;

        // ---- fused g update (LDS RMW) + next-step lane max/argmax group ----
        bestv = -1.0f; bestc = 0;
#pragma unroll
        for (int c = 0; c < 8; c++) {
            half8v gv = *(const half8v*)&g[c * 512 + lane8];
            H2x4 ug = __builtin_bit_cast(H2x4, gv);
            H2x4 uG = __builtin_bit_cast(H2x4, Gh[c]);
            ug.a -= sdh2 * uG.a; ug.b -= sdh2 * uG.b;
            ug.c -= sdh2 * uG.c; ug.d -= sdh2 * uG.d;
            *(half8v*)&g[c * 512 + lane8] = __builtin_bit_cast(half8v, ug);
            h2 g2 = hmax2(hmax2(habs2(ug.a), habs2(ug.b)),
                          hmax2(habs2(ug.c), habs2(ug.d)));
            float gm = fmaxf((float)g2[0], (float)g2[1]);
            if (gm > bestv) { bestv = gm; bestc = c; }
        }

        // ---- exact diagonal patch: g[bk] := fp16(bv - sd*||c_bk||^2).
        //      bestv may be stale-high by <=0.5 on one lane; MARGIN=1.5 covers
        //      it, the scan sees the patched value, and a stale argK is caught
        //      by the (nc==1 && cand[0]==argK) guard. ----
        if (lane == 0) g[bk] = (_Float16)(float)(bv - sd * cn2bk);

        // ---- exact fp64 residual update (winner row already in regs) ----
        rres[0] -= sd * (double)c0.x; rres[1] -= sd * (double)c0.y;
        rres[2] -= sd * (double)c0.z; rres[3] -= sd * (double)c0.w;
        rres[4] -= sd * (double)c1.x; rres[5] -= sd * (double)c1.y;
        rres[6] -= sd * (double)c1.z; rres[7] -= sd * (double)c1.w;
    }

    // ---- final residual (non-temporal) ----
    {
        f32x4 r0, r1;
        r0[0] = (float)rres[0]; r0[1] = (float)rres[1]; r0[2] = (float)rres[2]; r0[3] = (float)rres[3];
        r1[0] = (float)rres[4]; r1[1] = (float)rres[5]; r1[2] = (float)rres[6]; r1[3] = (float)rres[7];
        __builtin_nontemporal_store(r0, (f32x4*)(out_res + lane8));
        __builtin_nontemporal_store(r1, (f32x4*)(out_res + lane8 + 4));
    }
}

// ---------------------------------------------------------------------------
extern "C" void kernel_launch(void* const* d_in, const int* in_sizes, int n_in,
                              void* d_out, int out_size, void* d_ws, size_t ws_size,
                              hipStream_t stream) {
    const float* targets  = (const float*)d_in[0];
    const float* codebook = (const float*)d_in[1];
    float* out = (float*)d_out;

    __hip_bfloat16* abf = (__hip_bfloat16*)d_ws;                         // 12,582,912 B
    _Float16* S = (_Float16*)((char*)d_ws + (size_t)M_ALL * D_SZ * 2);   // 100,663,296 B
    double* cn2 = (double*)((char*)d_ws + (size_t)M_ALL * D_SZ * 2
                                        + (size_t)M_ALL * K_SZ * 2);     // 32,768 B
    // total ws needed: ~113.3 MB

    int total4 = (M_ALL * D_SZ) / 4;
    cast_bf16_kernel<<<(total4 + 255) / 256, 256, 0, stream>>>(targets, codebook, abf);
    cn2_kernel<<<K_SZ / 4, 256, 0, stream>>>(codebook, cn2);

    dim3 ggrid(K_SZ / BN, M_ALL / BM);   // 32 x 48 = 1536 blocks of 512 threads
    gemm_bt_kernel<<<ggrid, 512, 0, stream>>>(abf, abf + (size_t)B_SZ * D_SZ, S);

    pursuit_kernel<<<B_SZ / 4, 256, 0, stream>>>(targets, codebook, S, cn2, out);
}

// Round 9
// 355.390 us; speedup vs baseline: 1.1155x; 1.1155x over previous
//
#include <hip/hip_runtime.h>
#include <hip/hip_bf16.h>

// Problem constants
#define B_SZ 8192
#define D_SZ 512
#define K_SZ 4096
#define L_SZ 16
#define M_ALL (B_SZ + K_SZ)   // 12288 rows: targets stacked over codebook

typedef __attribute__((ext_vector_type(8))) short short8v;      // 8 bf16
typedef __attribute__((ext_vector_type(4))) float f32x4;
typedef _Float16 half8v __attribute__((ext_vector_type(8)));    // 8 fp16 = 16B
typedef _Float16 h2 __attribute__((ext_vector_type(2)));        // packed fp16 pair
struct H2x4 { h2 a, b, c, d; };                                 // = one half8v

typedef const __attribute__((address_space(1))) void gvoid;
typedef __attribute__((address_space(3))) void lvoid;

static __device__ __forceinline__ h2 habs2(h2 a) {
    unsigned u = __builtin_bit_cast(unsigned, a) & 0x7FFF7FFFu;
    return __builtin_bit_cast(h2, u);
}
static __device__ __forceinline__ h2 hmax2(h2 a, h2 b) {
#if __has_builtin(__builtin_elementwise_max)
    return __builtin_elementwise_max(a, b);
#else
    h2 r; r[0] = a[0] > b[0] ? a[0] : b[0]; r[1] = a[1] > b[1] ? a[1] : b[1]; return r;
#endif
}

// ---------------------------------------------------------------------------
// Kernel 1: cast targets+codebook (fp32) into one stacked bf16 matrix [12288 x 512]
// ---------------------------------------------------------------------------
__global__ void cast_bf16_kernel(const float* __restrict__ targets,
                                 const float* __restrict__ codebook,
                                 __hip_bfloat16* __restrict__ abf) {
    int idx = blockIdx.x * blockDim.x + threadIdx.x;
    const int total4 = (M_ALL * D_SZ) / 4;
    if (idx >= total4) return;
    int base = idx * 4;
    const float* src = (base < B_SZ * D_SZ) ? (targets + base)
                                            : (codebook + (base - B_SZ * D_SZ));
    float4 v = *(const float4*)src;
    abf[base + 0] = __float2bfloat16(v.x);
    abf[base + 1] = __float2bfloat16(v.y);
    abf[base + 2] = __float2bfloat16(v.z);
    abf[base + 3] = __float2bfloat16(v.w);
}

// ---------------------------------------------------------------------------
// Kernel 1b: exact fp64 codebook row norms^2 (for algebraic ||r||^2 update)
// ---------------------------------------------------------------------------
__global__ void cn2_kernel(const float* __restrict__ codebook,
                           double* __restrict__ cn2) {
    int row  = blockIdx.x * 4 + (threadIdx.x >> 6);
    int lane = threadIdx.x & 63;
    const float* r = codebook + (size_t)row * D_SZ;
    double s = 0.0;
#pragma unroll
    for (int j = 0; j < 8; j++) { double v = (double)r[lane + 64 * j]; s += v * v; }
#pragma unroll
    for (int o = 32; o > 0; o >>= 1) s += __shfl_down(s, o, 64);
    if (lane == 0) cn2[row] = s;
}

// ---------------------------------------------------------------------------
// Kernel 2: S = A * B^T -> fp16 [M x 4096]. 256x128 tile, 8 waves, BK=32,
// 16x16x32 MFMA. EXACT R6 version (best measured total 334.2 us).
// ---------------------------------------------------------------------------
#define BM 256
#define BN 128
#define BK 32   // bf16 elems: 64 B per LDS row, unpadded

__global__ __launch_bounds__(512)
void gemm_bt_kernel(const __hip_bfloat16* __restrict__ A,
                    const __hip_bfloat16* __restrict__ Bm,
                    _Float16* __restrict__ C) {
    __shared__ short As[BM * BK];   // 16 KB
    __shared__ short Bs[BN * BK];   // 8 KB
    const int tid  = threadIdx.x;
    const int bm   = blockIdx.y * BM;
    const int bn   = blockIdx.x * BN;
    const int wave = tid >> 6, lane = tid & 63;
    const int wm = (wave >> 1) * 64;     // 0,64,128,192
    const int wn = (wave & 1) * 64;      // 0,64
    const int row16 = lane & 15, quad = lane >> 4;
    const int koff = quad * 8;

    f32x4 acc[4][4] = {};

    const short* Ag = (const short*)A;
    const short* Bg = (const short*)Bm;
    const int srow = lane >> 2;          // 0..15 within a 16-row group
    const int scol = (lane & 3) * 8;     // elem offset 0/8/16/24 (16 B chunks)

    for (int k0 = 0; k0 < D_SZ; k0 += BK) {
        __syncthreads();   // protect previous iteration's fragment reads
        // A: 256 rows = 8 waves x 2 groups of 16
#pragma unroll
        for (int c = 0; c < 2; c++) {
            int row = wave * 32 + c * 16 + srow;
            __builtin_amdgcn_global_load_lds(
                (gvoid*)(Ag + (size_t)(bm + row) * D_SZ + k0 + scol),
                (lvoid*)(As + row * BK + scol), 16, 0, 0);
        }
        // B: 128 rows = 8 waves x 1 group of 16
        {
            int row = wave * 16 + srow;
            __builtin_amdgcn_global_load_lds(
                (gvoid*)(Bg + (size_t)(bn + row) * D_SZ + k0 + scol),
                (lvoid*)(Bs + row * BK + scol), 16, 0, 0);
        }
        __syncthreads();   // drains vmcnt -> LDS tiles complete

        short8v af[4], bf[4];
#pragma unroll
        for (int i = 0; i < 4; i++)
            af[i] = *(const short8v*)(As + (wm + i * 16 + row16) * BK + koff);
#pragma unroll
        for (int j = 0; j < 4; j++)
            bf[j] = *(const short8v*)(Bs + (wn + j * 16 + row16) * BK + koff);
#pragma unroll
        for (int i = 0; i < 4; i++)
#pragma unroll
            for (int j = 0; j < 4; j++)
                acc[i][j] = __builtin_amdgcn_mfma_f32_16x16x32_bf16(af[i], bf[j], acc[i][j], 0, 0, 0);
    }

    // C/D layout: col = lane&15, row = quad*4 + reg  [m89/m91 verified]
    if (bm < B_SZ) {
        // score region: written once, read once by pursuit -> non-temporal
#pragma unroll
        for (int i = 0; i < 4; i++) {
            int grow = bm + wm + i * 16 + quad * 4;
#pragma unroll
            for (int j = 0; j < 4; j++) {
                int gcol = bn + wn + j * 16 + row16;
#pragma unroll
                for (int r = 0; r < 4; r++)
                    __builtin_nontemporal_store((_Float16)acc[i][j][r],
                                                &C[(size_t)(grow + r) * K_SZ + gcol]);
            }
        }
    } else {
        // Gram region: hot random-access data for pursuit -> keep cached
#pragma unroll
        for (int i = 0; i < 4; i++) {
            int grow = bm + wm + i * 16 + quad * 4;
#pragma unroll
            for (int j = 0; j < 4; j++) {
                int gcol = bn + wn + j * 16 + row16;
#pragma unroll
                for (int r = 0; r < 4; r++)
                    C[(size_t)(grow + r) * K_SZ + gcol] = (_Float16)acc[i][j][r];
            }
        }
    }
}

// ---------------------------------------------------------------------------
// Kernel 3: pursuit, wave-per-row, g in LDS (round-0 structure, proven 208us)
// with ONE change: candidate collection moved from LDS cnt/cand + atomics to
// PER-LANE REGISTERS + __ballot.  This shrinks LDS from 33,280 B to exactly
// 32,768 B -> 5 blocks/CU instead of 4 (163,840/32,768 = 5.0) -> wave cap
// 16 -> 20 per CU.  Achieved fetch BW has tracked the LDS wave cap across
// all rounds (R3 2-blk: 1.9 TB/s, R0 4-blk: 2.86 TB/s); pursuit dur ==
// FETCH/BW, so +25% cap should give ~3.3-3.6 TB/s.
// Candidate semantics: 4 named regs/lane (statically indexed, rule #20),
// wave-uniform __ffsll iteration over the ballot mask; winner = max |s|,
// tie -> min index (identical to round-0; per-lane cap 4 replaces the old
// total cap 16 -- both unreachable for Gaussian scores with MARGIN=1.5).
// R8's speculative prefetch reverted (FETCH +38% on mispredicts).
// ---------------------------------------------------------------------------
#define MARGIN 1.5f

__global__ __launch_bounds__(256, 5)
void pursuit_kernel(const float* __restrict__ targets,
                    const float* __restrict__ codebook,
                    const _Float16* __restrict__ S,   // [12288 x 4096]; rows >=8192 are Gram
                    const double* __restrict__ cn2,   // [4096] exact ||c_k||^2
                    float* __restrict__ out) {
    const int wave = threadIdx.x >> 6;
    const int lane = threadIdx.x & 63;
    const int b = blockIdx.x * 4 + wave;
    const int lane8 = lane * 8;

    __shared__ alignas(16) _Float16 g_s[4][K_SZ];   // exactly 32,768 B
    _Float16* g = g_s[wave];

    // ---- init: score row -> LDS (non-temporal), lane max in flight ----
    h2 tmax; tmax[0] = (_Float16)0; tmax[1] = (_Float16)0;
    {
        const _Float16* g0 = S + (size_t)b * K_SZ + lane8;
#pragma unroll
        for (int c = 0; c < 8; c++) {
            half8v h = __builtin_nontemporal_load((const half8v*)(g0 + c * 512));
            *(half8v*)&g[c * 512 + lane8] = h;
            H2x4 u = __builtin_bit_cast(H2x4, h);
            tmax = hmax2(tmax, hmax2(hmax2(habs2(u.a), habs2(u.b)),
                                     hmax2(habs2(u.c), habs2(u.d))));
        }
    }
    float m = fmaxf((float)tmax[0], (float)tmax[1]);

    // ---- lane-private fp64 residual + tn2 (non-temporal target read) ----
    double rres[8];
    double loc = 0.0;
    {
        const float* tg = targets + (size_t)b * D_SZ + lane8;
        f32x4 t0 = __builtin_nontemporal_load((const f32x4*)tg);
        f32x4 t1 = __builtin_nontemporal_load((const f32x4*)(tg + 4));
        rres[0] = t0[0]; rres[1] = t0[1]; rres[2] = t0[2]; rres[3] = t0[3];
        rres[4] = t1[0]; rres[5] = t1[1]; rres[6] = t1[2]; rres[7] = t1[3];
#pragma unroll
        for (int e = 0; e < 8; e++) loc += rres[e] * rres[e];
    }
#pragma unroll
    for (int o = 32; o > 0; o >>= 1) loc += __shfl_xor(loc, o, 64);
    double rn2 = loc;
    const bool tgt_ok = (sqrt(loc) >= 1e-8);

    float* out_seq  = out + (size_t)b * L_SZ;
    float* out_mask = out + (size_t)B_SZ * L_SZ + (size_t)b * L_SZ;
    float* out_res  = out + (size_t)2 * B_SZ * L_SZ + (size_t)b * D_SZ;

    double decay = 1.0;

    for (int t = 0; t < L_SZ; t++) {
        decay *= 0.95;
        bool active = (sqrt(rn2) >= 0.01) && tgt_ok;   // wave-uniform
        if (!active) {                                 // stays inactive forever
            if (lane == 0)
                for (int tt = t; tt < L_SZ; tt++) {
                    __builtin_nontemporal_store(0.0f, &out_seq[tt]);
                    __builtin_nontemporal_store(0.0f, &out_mask[tt]);
                }
            break;
        }

        // ---- wave max + threshold ----
        float M = m;
#pragma unroll
        for (int o = 32; o > 0; o >>= 1) M = fmaxf(M, __shfl_xor(M, o, 64));
        float thr = M - MARGIN;

        // ---- candidate collection: per-lane registers + ballot (no LDS) ----
        int mc0 = 0, mc1 = 0, mc2 = 0, mc3 = 0;   // named regs, static indexing
        int mycnt = 0;
        if (m >= thr) {
#pragma unroll
            for (int c = 0; c < 8; c++) {
                half8v h = *(const half8v*)&g[c * 512 + lane8];
#pragma unroll
                for (int e = 0; e < 8; e++) {
                    float f = fabsf((float)h[e]);
                    if (f >= thr) {
                        int idx = c * 512 + lane8 + e;
                        if      (mycnt == 0) mc0 = idx;
                        else if (mycnt == 1) mc1 = idx;
                        else if (mycnt == 2) mc2 = idx;
                        else if (mycnt == 3) mc3 = idx;
                        mycnt++;
                    }
                }
            }
        }
        unsigned long long ball = __ballot(mycnt > 0);
        const int nlanes = __popcll(ball);
        const int firstl = __ffsll((unsigned long long)ball) - 1;
        const int fcnt   = __shfl(mycnt, firstl, 64);

        // ---- exact fp64 rescore; Gram loads hoisted off the tail ----
        int bk; double bv;
        float4 c0, c1;
        half8v Gh[8];
        if (nlanes == 1 && fcnt == 1) {
            // single candidate (common): load + deferred dot
            bk = __shfl(mc0, firstl, 64);
            const float* cr = codebook + (size_t)bk * D_SZ + lane8;
            const _Float16* Gp = S + (size_t)(B_SZ + bk) * K_SZ + lane8;
            c0 = *(const float4*)cr;
            c1 = *(const float4*)(cr + 4);
#pragma unroll
            for (int c = 0; c < 8; c++) Gh[c] = *(const half8v*)(Gp + c * 512);
            double s = rres[0] * (double)c0.x + rres[1] * (double)c0.y
                     + rres[2] * (double)c0.z + rres[3] * (double)c0.w
                     + rres[4] * (double)c1.x + rres[5] * (double)c1.y
                     + rres[6] * (double)c1.z + rres[7] * (double)c1.w;
#pragma unroll
            for (int o = 32; o > 0; o >>= 1) s += __shfl_xor(s, o, 64);
            bv = s;
        } else {
            bk = -1; bv = 0.0;
            auto rescore = [&](int k) {
                const float* cr = codebook + (size_t)k * D_SZ + lane8;
                float4 d0 = *(const float4*)cr;
                float4 d1 = *(const float4*)(cr + 4);
                double s = rres[0] * (double)d0.x + rres[1] * (double)d0.y
                         + rres[2] * (double)d0.z + rres[3] * (double)d0.w
                         + rres[4] * (double)d1.x + rres[5] * (double)d1.y
                         + rres[6] * (double)d1.z + rres[7] * (double)d1.w;
#pragma unroll
                for (int o = 32; o > 0; o >>= 1) s += __shfl_xor(s, o, 64);
                if (bk < 0 || fabs(s) > fabs(bv) ||
                    (fabs(s) == fabs(bv) && k < bk)) { bk = k; bv = s; }
            };
            unsigned long long rem = ball;
            while (rem) {
                int l = __ffsll((unsigned long long)rem) - 1;
                rem &= rem - 1;
                int cl = __shfl(mycnt, l, 64);       // wave-uniform
                int k0 = __shfl(mc0, l, 64), k1 = __shfl(mc1, l, 64);
                int k2 = __shfl(mc2, l, 64), k3 = __shfl(mc3, l, 64);
                rescore(k0);
                if (cl > 1) rescore(k1);
                if (cl > 2) rescore(k2);
                if (cl > 3) rescore(k3);
            }
            const float* cr = codebook + (size_t)bk * D_SZ + lane8;   // winner row
            const _Float16* Gp = S + (size_t)(B_SZ + bk) * K_SZ + lane8;
            c0 = *(const float4*)cr;
            c1 = *(const float4*)(cr + 4);
#pragma unroll
            for (int c = 0; c < 8; c++) Gh[c] = *(const half8v*)(Gp + c * 512);
        }

        // ---- decision + exact ||r||^2 identity + outputs ----
        const double cn2bk = cn2[bk];
        double sd = ((bv >= 0.0) ? 1.0 : -1.0) * decay;
        rn2 = rn2 - 2.0 * sd * bv + sd * sd * cn2bk;
        if (lane == 0) {
            __builtin_nontemporal_store((float)((bv >= 0.0) ? bk : (-bk - 1)), &out_seq[t]);
            __builtin_nontemporal_store(1.0f, &out_mask[t]);
        }
        const float sdf = (float)sd;
        h2 sdh2; sdh2[0] = (_Float16)sdf; sdh2[1] = (_Float16)sdf;

        // ---- fused g update (LDS RMW) + next-step lane max ----
        tmax[0] = (_Float16)0; tmax[1] = (_Float16)0;
#pragma unroll
        for (int c = 0; c < 8; c++) {
            half8v gv = *(const half8v*)&g[c * 512 + lane8];
            H2x4 ug = __builtin_bit_cast(H2x4, gv);
            H2x4 uG = __builtin_bit_cast(H2x4, Gh[c]);
            ug.a -= sdh2 * uG.a; ug.b -= sdh2 * uG.b;
            ug.c -= sdh2 * uG.c; ug.d -= sdh2 * uG.d;
            *(half8v*)&g[c * 512 + lane8] = __builtin_bit_cast(half8v, ug);
            tmax = hmax2(tmax, hmax2(hmax2(habs2(ug.a), habs2(ug.b)),
                                     hmax2(habs2(ug.c), habs2(ug.d))));
        }
        m = fmaxf((float)tmax[0], (float)tmax[1]);

        // ---- exact diagonal patch: g[bk] := fp16(bv - sd*||c_bk||^2).
        //      m may be stale-high by <=0.5 on one lane; MARGIN=1.5 covers it,
        //      and the candidate re-read above sees the patched value. ----
        if (lane == 0) g[bk] = (_Float16)(float)(bv - sd * cn2bk);

        // ---- exact fp64 residual update (winner row already in regs) ----
        rres[0] -= sd * (double)c0.x; rres[1] -= sd * (double)c0.y;
        rres[2] -= sd * (double)c0.z; rres[3] -= sd * (double)c0.w;
        rres[4] -= sd * (double)c1.x; rres[5] -= sd * (double)c1.y;
        rres[6] -= sd * (double)c1.z; rres[7] -= sd * (double)c1.w;
    }

    // ---- final residual (non-temporal) ----
    {
        f32x4 r0, r1;
        r0[0] = (float)rres[0]; r0[1] = (float)rres[1]; r0[2] = (float)rres[2]; r0[3] = (float)rres[3];
        r1[0] = (float)rres[4]; r1[1] = (float)rres[5]; r1[2] = (float)rres[6]; r1[3] = (float)rres[7];
        __builtin_nontemporal_store(r0, (f32x4*)(out_res + lane8));
        __builtin_nontemporal_store(r1, (f32x4*)(out_res + lane8 + 4));
    }
}

// ---------------------------------------------------------------------------
extern "C" void kernel_launch(void* const* d_in, const int* in_sizes, int n_in,
                              void* d_out, int out_size, void* d_ws, size_t ws_size,
                              hipStream_t stream) {
    const float* targets  = (const float*)d_in[0];
    const float* codebook = (const float*)d_in[1];
    float* out = (float*)d_out;

    __hip_bfloat16* abf = (__hip_bfloat16*)d_ws;                         // 12,582,912 B
    _Float16* S = (_Float16*)((char*)d_ws + (size_t)M_ALL * D_SZ * 2);   // 100,663,296 B
    double* cn2 = (double*)((char*)d_ws + (size_t)M_ALL * D_SZ * 2
                                        + (size_t)M_ALL * K_SZ * 2);     // 32,768 B
    // total ws needed: ~113.3 MB

    int total4 = (M_ALL * D_SZ) / 4;
    cast_bf16_kernel<<<(total4 + 255) / 256, 256, 0, stream>>>(targets, codebook, abf);
    cn2_kernel<<<K_SZ / 4, 256, 0, stream>>>(codebook, cn2);

    dim3 ggrid(K_SZ / BN, M_ALL / BM);   // 32 x 48 = 1536 blocks of 512 threads
    gemm_bt_kernel<<<ggrid, 512, 0, stream>>>(abf, abf + (size_t)B_SZ * D_SZ, S);

    pursuit_kernel<<<B_SZ / 4, 256, 0, stream>>>(targets, codebook, S, cn2, out);
}

// Round 10
// 335.698 us; speedup vs baseline: 1.1809x; 1.0587x over previous
//
#include <hip/hip_runtime.h>
#include <hip/hip_bf16.h>

// Problem constants
#define B_SZ 8192
#define D_SZ 512
#define K_SZ 4096
#define L_SZ 16
#define M_ALL (B_SZ + K_SZ)   // 12288 rows: targets stacked over codebook

typedef __attribute__((ext_vector_type(8))) short short8v;      // 8 bf16
typedef __attribute__((ext_vector_type(4))) float f32x4;
typedef _Float16 half8v __attribute__((ext_vector_type(8)));    // 8 fp16 = 16B
typedef _Float16 h2 __attribute__((ext_vector_type(2)));        // packed fp16 pair
struct H2x4 { h2 a, b, c, d; };                                 // = one half8v

typedef const __attribute__((address_space(1))) void gvoid;
typedef __attribute__((address_space(3))) void lvoid;

static __device__ __forceinline__ h2 habs2(h2 a) {
    unsigned u = __builtin_bit_cast(unsigned, a) & 0x7FFF7FFFu;
    return __builtin_bit_cast(h2, u);
}
static __device__ __forceinline__ h2 hmax2(h2 a, h2 b) {
#if __has_builtin(__builtin_elementwise_max)
    return __builtin_elementwise_max(a, b);
#else
    h2 r; r[0] = a[0] > b[0] ? a[0] : b[0]; r[1] = a[1] > b[1] ? a[1] : b[1]; return r;
#endif
}

// ---------------------------------------------------------------------------
// Kernel 1: cast targets+codebook (fp32) into one stacked bf16 matrix [12288 x 512]
// ---------------------------------------------------------------------------
__global__ void cast_bf16_kernel(const float* __restrict__ targets,
                                 const float* __restrict__ codebook,
                                 __hip_bfloat16* __restrict__ abf) {
    int idx = blockIdx.x * blockDim.x + threadIdx.x;
    const int total4 = (M_ALL * D_SZ) / 4;
    if (idx >= total4) return;
    int base = idx * 4;
    const float* src = (base < B_SZ * D_SZ) ? (targets + base)
                                            : (codebook + (base - B_SZ * D_SZ));
    float4 v = *(const float4*)src;
    abf[base + 0] = __float2bfloat16(v.x);
    abf[base + 1] = __float2bfloat16(v.y);
    abf[base + 2] = __float2bfloat16(v.z);
    abf[base + 3] = __float2bfloat16(v.w);
}

// ---------------------------------------------------------------------------
// Kernel 1b: exact fp64 codebook row norms^2 (for algebraic ||r||^2 update)
// ---------------------------------------------------------------------------
__global__ void cn2_kernel(const float* __restrict__ codebook,
                           double* __restrict__ cn2) {
    int row  = blockIdx.x * 4 + (threadIdx.x >> 6);
    int lane = threadIdx.x & 63;
    const float* r = codebook + (size_t)row * D_SZ;
    double s = 0.0;
#pragma unroll
    for (int j = 0; j < 8; j++) { double v = (double)r[lane + 64 * j]; s += v * v; }
#pragma unroll
    for (int o = 32; o > 0; o >>= 1) s += __shfl_down(s, o, 64);
    if (lane == 0) cn2[row] = s;
}

// ---------------------------------------------------------------------------
// Kernel 2: S = A * B^T -> fp16 [M x 4096]. 256x128 tile, EIGHT waves
// (512 threads), BK=32, 16x16x32 MFMA, m97-style global_load_lds staging.
// EXACT R6 version (best measured total 334.2 us). Scheduling variants
// (BK=64+chunk-swizzle, packed epilogue, 2-phase dbuf) all neutral-to-
// negative: 51.5 GFLOP at ~460 TF matches the m97-structure shape curve
// at K=512; further gains need the full 8-phase rewrite (race-screen
// requirements exceed this harness -- not shipped).
// ---------------------------------------------------------------------------
#define BM 256
#define BN 128
#define BK 32   // bf16 elems: 64 B per LDS row, unpadded

__global__ __launch_bounds__(512)
void gemm_bt_kernel(const __hip_bfloat16* __restrict__ A,
                    const __hip_bfloat16* __restrict__ Bm,
                    _Float16* __restrict__ C) {
    __shared__ short As[BM * BK];   // 16 KB
    __shared__ short Bs[BN * BK];   // 8 KB
    const int tid  = threadIdx.x;
    const int bm   = blockIdx.y * BM;
    const int bn   = blockIdx.x * BN;
    const int wave = tid >> 6, lane = tid & 63;
    const int wm = (wave >> 1) * 64;     // 0,64,128,192
    const int wn = (wave & 1) * 64;      // 0,64
    const int row16 = lane & 15, quad = lane >> 4;
    const int koff = quad * 8;

    f32x4 acc[4][4] = {};

    const short* Ag = (const short*)A;
    const short* Bg = (const short*)Bm;
    const int srow = lane >> 2;          // 0..15 within a 16-row group
    const int scol = (lane & 3) * 8;     // elem offset 0/8/16/24 (16 B chunks)

    for (int k0 = 0; k0 < D_SZ; k0 += BK) {
        __syncthreads();   // protect previous iteration's fragment reads
        // A: 256 rows = 8 waves x 2 groups of 16
#pragma unroll
        for (int c = 0; c < 2; c++) {
            int row = wave * 32 + c * 16 + srow;
            __builtin_amdgcn_global_load_lds(
                (gvoid*)(Ag + (size_t)(bm + row) * D_SZ + k0 + scol),
                (lvoid*)(As + row * BK + scol), 16, 0, 0);
        }
        // B: 128 rows = 8 waves x 1 group of 16
        {
            int row = wave * 16 + srow;
            __builtin_amdgcn_global_load_lds(
                (gvoid*)(Bg + (size_t)(bn + row) * D_SZ + k0 + scol),
                (lvoid*)(Bs + row * BK + scol), 16, 0, 0);
        }
        __syncthreads();   // drains vmcnt -> LDS tiles complete

        short8v af[4], bf[4];
#pragma unroll
        for (int i = 0; i < 4; i++)
            af[i] = *(const short8v*)(As + (wm + i * 16 + row16) * BK + koff);
#pragma unroll
        for (int j = 0; j < 4; j++)
            bf[j] = *(const short8v*)(Bs + (wn + j * 16 + row16) * BK + koff);
#pragma unroll
        for (int i = 0; i < 4; i++)
#pragma unroll
            for (int j = 0; j < 4; j++)
                acc[i][j] = __builtin_amdgcn_mfma_f32_16x16x32_bf16(af[i], bf[j], acc[i][j], 0, 0, 0);
    }

    // C/D layout: col = lane&15, row = quad*4 + reg  [m89/m91 verified]
    if (bm < B_SZ) {
        // score region: written once, read once by pursuit -> non-temporal
#pragma unroll
        for (int i = 0; i < 4; i++) {
            int grow = bm + wm + i * 16 + quad * 4;
#pragma unroll
            for (int j = 0; j < 4; j++) {
                int gcol = bn + wn + j * 16 + row16;
#pragma unroll
                for (int r = 0; r < 4; r++)
                    __builtin_nontemporal_store((_Float16)acc[i][j][r],
                                                &C[(size_t)(grow + r) * K_SZ + gcol]);
            }
        }
    } else {
        // Gram region: hot random-access data for pursuit -> keep cached
#pragma unroll
        for (int i = 0; i < 4; i++) {
            int grow = bm + wm + i * 16 + quad * 4;
#pragma unroll
            for (int j = 0; j < 4; j++) {
                int gcol = bn + wn + j * 16 + row16;
#pragma unroll
                for (int r = 0; r < 4; r++)
                    C[(size_t)(grow + r) * K_SZ + gcol] = (_Float16)acc[i][j][r];
            }
        }
    }
}

// ---------------------------------------------------------------------------
// Kernel 3: pursuit, wave-per-row, g in LDS as fp16 (8 KB/row, linear,
// conflict-free b128). EXACT round-0 version -- the proven optimum.
// Evidence summary (rounds 1,2,3,8,9): reg-g spilled to scratch (+12us);
// 2-wave blocks cut achieved concurrency (+23us); 2-chain waves halved TLP
// (+130us); speculative argmax prefetch inflated FETCH 38% (+44us); ballot
// register candidates added fetch+VALU (+20us). dur == FETCH/2.8TB/s, the
// contention-limited random-access rate at ~12 achieved waves/CU; fetch
// volume (8KB Gram row + 8KB g scan/update x 16 steps x 8192 rows) is
// algorithmically mandatory.
// ---------------------------------------------------------------------------
#define MAXC 16
#define MARGIN 1.5f

__global__ __launch_bounds__(256, 4)
void pursuit_kernel(const float* __restrict__ targets,
                    const float* __restrict__ codebook,
                    const _Float16* __restrict__ S,   // [12288 x 4096]; rows >=8192 are Gram
                    const double* __restrict__ cn2,   // [4096] exact ||c_k||^2
                    float* __restrict__ out) {
    const int wave = threadIdx.x >> 6;
    const int lane = threadIdx.x & 63;
    const int b = blockIdx.x * 4 + wave;
    const int lane8 = lane * 8;

    __shared__ alignas(16) _Float16 g_s[4][K_SZ];
    __shared__ int s_cnt[4];
    __shared__ int s_cand[4][MAXC];
    _Float16* g = g_s[wave];
    int* cnt  = &s_cnt[wave];
    int* cand = s_cand[wave];

    // ---- init: score row -> LDS (non-temporal), lane max in flight ----
    h2 tmax; tmax[0] = (_Float16)0; tmax[1] = (_Float16)0;
    {
        const _Float16* g0 = S + (size_t)b * K_SZ + lane8;
#pragma unroll
        for (int c = 0; c < 8; c++) {
            half8v h = __builtin_nontemporal_load((const half8v*)(g0 + c * 512));
            *(half8v*)&g[c * 512 + lane8] = h;
            H2x4 u = __builtin_bit_cast(H2x4, h);
            tmax = hmax2(tmax, hmax2(hmax2(habs2(u.a), habs2(u.b)),
                                     hmax2(habs2(u.c), habs2(u.d))));
        }
    }
    float m = fmaxf((float)tmax[0], (float)tmax[1]);

    // ---- lane-private fp64 residual + tn2 (non-temporal target read) ----
    double rres[8];
    double loc = 0.0;
    {
        const float* tg = targets + (size_t)b * D_SZ + lane8;
        f32x4 t0 = __builtin_nontemporal_load((const f32x4*)tg);
        f32x4 t1 = __builtin_nontemporal_load((const f32x4*)(tg + 4));
        rres[0] = t0[0]; rres[1] = t0[1]; rres[2] = t0[2]; rres[3] = t0[3];
        rres[4] = t1[0]; rres[5] = t1[1]; rres[6] = t1[2]; rres[7] = t1[3];
#pragma unroll
        for (int e = 0; e < 8; e++) loc += rres[e] * rres[e];
    }
#pragma unroll
    for (int o = 32; o > 0; o >>= 1) loc += __shfl_xor(loc, o, 64);
    double rn2 = loc;
    const bool tgt_ok = (sqrt(loc) >= 1e-8);

    float* out_seq  = out + (size_t)b * L_SZ;
    float* out_mask = out + (size_t)B_SZ * L_SZ + (size_t)b * L_SZ;
    float* out_res  = out + (size_t)2 * B_SZ * L_SZ + (size_t)b * D_SZ;

    double decay = 1.0;

    for (int t = 0; t < L_SZ; t++) {
        decay *= 0.95;
        bool active = (sqrt(rn2) >= 0.01) && tgt_ok;   // wave-uniform
        if (!active) {                                 // stays inactive forever
            if (lane == 0)
                for (int tt = t; tt < L_SZ; tt++) {
                    __builtin_nontemporal_store(0.0f, &out_seq[tt]);
                    __builtin_nontemporal_store(0.0f, &out_mask[tt]);
                }
            break;
        }

        // ---- wave max + threshold ----
        float M = m;
#pragma unroll
        for (int o = 32; o > 0; o >>= 1) M = fmaxf(M, __shfl_xor(M, o, 64));
        float thr = M - MARGIN;

        // ---- candidate collection: re-read LDS under divergent guard ----
        if (lane == 0) *cnt = 0;
        if (m >= thr) {
#pragma unroll
            for (int c = 0; c < 8; c++) {
                half8v h = *(const half8v*)&g[c * 512 + lane8];
#pragma unroll
                for (int e = 0; e < 8; e++) {
                    float f = fabsf((float)h[e]);
                    if (f >= thr) {
                        int q = atomicAdd(cnt, 1);
                        if (q < MAXC) cand[q] = c * 512 + lane8 + e;
                    }
                }
            }
        }
        __threadfence_block();
        int nc = min(*cnt, MAXC);

        // ---- exact fp64 rescore; Gram loads hoisted off the tail ----
        int bk; double bv;
        float4 c0, c1;
        half8v Gh[8];
        if (nc == 1) {
            bk = __builtin_amdgcn_readfirstlane(cand[0]);
            const float* cr = codebook + (size_t)bk * D_SZ + lane8;
            const _Float16* Gp = S + (size_t)(B_SZ + bk) * K_SZ + lane8;
            c0 = *(const float4*)cr;
            c1 = *(const float4*)(cr + 4);
#pragma unroll
            for (int c = 0; c < 8; c++) Gh[c] = *(const half8v*)(Gp + c * 512);
            double s = rres[0] * (double)c0.x + rres[1] * (double)c0.y
                     + rres[2] * (double)c0.z + rres[3] * (double)c0.w
                     + rres[4] * (double)c1.x + rres[5] * (double)c1.y
                     + rres[6] * (double)c1.z + rres[7] * (double)c1.w;
#pragma unroll
            for (int o = 32; o > 0; o >>= 1) s += __shfl_xor(s, o, 64);
            bv = s;
        } else {
            bk = -1; bv = 0.0;
            for (int ci = 0; ci < nc; ci++) {
                int k = __builtin_amdgcn_readfirstlane(cand[ci]);
                const float* cr = codebook + (size_t)k * D_SZ + lane8;
                float4 d0 = *(const float4*)cr;
                float4 d1 = *(const float4*)(cr + 4);
                double s = rres[0] * (double)d0.x + rres[1] * (double)d0.y
                         + rres[2] * (double)d0.z + rres[3] * (double)d0.w
                         + rres[4] * (double)d1.x + rres[5] * (double)d1.y
                         + rres[6] * (double)d1.z + rres[7] * (double)d1.w;
#pragma unroll
                for (int o = 32; o > 0; o >>= 1) s += __shfl_xor(s, o, 64);
                if (bk < 0 || fabs(s) > fabs(bv) ||
                    (fabs(s) == fabs(bv) && k < bk)) { bk = k; bv = s; }
            }
            const float* cr = codebook + (size_t)bk * D_SZ + lane8;   // winner row
            const _Float16* Gp = S + (size_t)(B_SZ + bk) * K_SZ + lane8;
            c0 = *(const float4*)cr;
            c1 = *(const float4*)(cr + 4);
#pragma unroll
            for (int c = 0; c < 8; c++) Gh[c] = *(const half8v*)(Gp + c * 512);
        }

        // ---- decision + exact ||r||^2 identity + outputs ----
        const double cn2bk = cn2[bk];
        double sd = ((bv >= 0.0) ? 1.0 : -1.0) * decay;
        rn2 = rn2 - 2.0 * sd * bv + sd * sd * cn2bk;
        if (lane == 0) {
            __builtin_nontemporal_store((float)((bv >= 0.0) ? bk : (-bk - 1)), &out_seq[t]);
            __builtin_nontemporal_store(1.0f, &out_mask[t]);
        }
        const float sdf = (float)sd;
        h2 sdh2; sdh2[0] = (_Float16)sdf; sdh2[1] = (_Float16)sdf;

        // ---- fused g update (LDS RMW) + next-step lane max ----
        tmax[0] = (_Float16)0; tmax[1] = (_Float16)0;
#pragma unroll
        for (int c = 0; c < 8; c++) {
            half8v gv = *(const half8v*)&g[c * 512 + lane8];
            H2x4 ug = __builtin_bit_cast(H2x4, gv);
            H2x4 uG = __builtin_bit_cast(H2x4, Gh[c]);
            ug.a -= sdh2 * uG.a; ug.b -= sdh2 * uG.b;
            ug.c -= sdh2 * uG.c; ug.d -= sdh2 * uG.d;
            *(half8v*)&g[c * 512 + lane8] = __builtin_bit_cast(half8v, ug);
            tmax = hmax2(tmax, hmax2(hmax2(habs2(ug.a), habs2(ug.b)),
                                     hmax2(habs2(ug.c), habs2(ug.d))));
        }
        m = fmaxf((float)tmax[0], (float)tmax[1]);

        // ---- exact diagonal patch: g[bk] := fp16(bv - sd*||c_bk||^2).
        //      m may be stale-high by <=0.5 on one lane; MARGIN=1.5 covers it,
        //      and the candidate re-read above sees the patched value. ----
        if (lane == 0) g[bk] = (_Float16)(float)(bv - sd * cn2bk);

        // ---- exact fp64 residual update (winner row already in regs) ----
        rres[0] -= sd * (double)c0.x; rres[1] -= sd * (double)c0.y;
        rres[2] -= sd * (double)c0.z; rres[3] -= sd * (double)c0.w;
        rres[4] -= sd * (double)c1.x; rres[5] -= sd * (double)c1.y;
        rres[6] -= sd * (double)c1.z; rres[7] -= sd * (double)c1.w;
    }

    // ---- final residual (non-temporal) ----
    {
        f32x4 r0, r1;
        r0[0] = (float)rres[0]; r0[1] = (float)rres[1]; r0[2] = (float)rres[2]; r0[3] = (float)rres[3];
        r1[0] = (float)rres[4]; r1[1] = (float)rres[5]; r1[2] = (float)rres[6]; r1[3] = (float)rres[7];
        __builtin_nontemporal_store(r0, (f32x4*)(out_res + lane8));
        __builtin_nontemporal_store(r1, (f32x4*)(out_res + lane8 + 4));
    }
}

// ---------------------------------------------------------------------------
extern "C" void kernel_launch(void* const* d_in, const int* in_sizes, int n_in,
                              void* d_out, int out_size, void* d_ws, size_t ws_size,
                              hipStream_t stream) {
    const float* targets  = (const float*)d_in[0];
    const float* codebook = (const float*)d_in[1];
    float* out = (float*)d_out;

    __hip_bfloat16* abf = (__hip_bfloat16*)d_ws;                         // 12,582,912 B
    _Float16* S = (_Float16*)((char*)d_ws + (size_t)M_ALL * D_SZ * 2);   // 100,663,296 B
    double* cn2 = (double*)((char*)d_ws + (size_t)M_ALL * D_SZ * 2
                                        + (size_t)M_ALL * K_SZ * 2);     // 32,768 B
    // total ws needed: ~113.3 MB

    int total4 = (M_ALL * D_SZ) / 4;
    cast_bf16_kernel<<<(total4 + 255) / 256, 256, 0, stream>>>(targets, codebook, abf);
    cn2_kernel<<<K_SZ / 4, 256, 0, stream>>>(codebook, cn2);

    dim3 ggrid(K_SZ / BN, M_ALL / BM);   // 32 x 48 = 1536 blocks of 512 threads
    gemm_bt_kernel<<<ggrid, 512, 0, stream>>>(abf, abf + (size_t)B_SZ * D_SZ, S);

    pursuit_kernel<<<B_SZ / 4, 256, 0, stream>>>(targets, codebook, S, cn2, out);
}